// Round 9
// baseline (323.488 us; speedup 1.0000x reference)
//
#include <hip/hip_runtime.h>

typedef _Float16 f16;
typedef __attribute__((ext_vector_type(8))) _Float16 f16x8;
typedef __attribute__((ext_vector_type(4))) _Float16 f16x4;
typedef __attribute__((ext_vector_type(4))) float floatx4;

#define MFMA16(a, b, c) __builtin_amdgcn_mfma_f32_16x16x32_f16(a, b, c, 0, 0, 0)

#define BATCH 32
#define LQ 512
#define LK 512
#define DIM 1024

#define BARRIER() __builtin_amdgcn_s_barrier()
#define CFENCE() asm volatile("" ::: "memory")
#define WAITVM(n) asm volatile("s_waitcnt vmcnt(" #n ")" ::: "memory")

// async global->LDS, 16B per lane. Lessons: r4 — never pre-swizzle the global
// source (breaks coalescing); r3/r6 — never grow LDS past 32KB on the 128^2
// GEMMs (co-residency loss raises L2 misses).
__device__ __forceinline__ void glds16(const void* g, void* l) {
    __builtin_amdgcn_global_load_lds(
        (const __attribute__((address_space(1))) unsigned int*)g,
        (__attribute__((address_space(3))) unsigned int*)l, 16, 0, 0);
}

// ===========================================================================
// K_prep fused, 512 thr, 1536 blocks. Big-tile rework (r8 post-mortem:
// 2.37 TB/s, VGPR=28 -> serialized; 128B write segments):
//   bid [0,256):     io 256x256 tiles -> Y16 + YT (512B write segs, 1 barrier)
//   bid [256,1280):  X16 = fp16(ix), load-batched (8 loads in flight)
//   bid [1280,1408): WT 64e x 128d transpose tiles
//   bid [1408,1536): partial[es][d] = sum_{e in 128-chunk} W[e][d]*bias[e]
// ===========================================================================
__global__ __launch_bounds__(512) void k_prep_f(const float* __restrict__ ix,
                                                const float* __restrict__ io,
                                                const float* __restrict__ W,
                                                const float* __restrict__ bias,
                                                f16* __restrict__ X16,
                                                f16* __restrict__ Y16,
                                                f16* __restrict__ YT,
                                                f16* __restrict__ WT,
                                                float* __restrict__ partial) {
    __shared__ __align__(16) char Sraw[135168];  // 256 x 264 f16
    const int bid = blockIdx.x;
    const int t = threadIdx.x;
    if (bid < 256) {  // ---- io 256x256 tile: fp32 -> Y16 (row) + YT (col) ----
        f16(*S)[264] = (f16(*)[264])Sraw;
        const int b = bid >> 3;
        const int m0 = ((bid >> 2) & 1) * 256, d0 = (bid & 3) * 256;
        const int row_t = t >> 4, col = (t & 15) * 16;  // 32 rows/pass, 64B/thr
#pragma unroll
        for (int u = 0; u < 8; ++u) {
            int row = u * 32 + row_t;
            const float* src = io + (size_t)(b * LK + m0 + row) * DIM + d0 + col;
            floatx4 v0 = *(const floatx4*)(src);
            floatx4 v1 = *(const floatx4*)(src + 4);
            floatx4 v2 = *(const floatx4*)(src + 8);
            floatx4 v3 = *(const floatx4*)(src + 12);
            union { f16 h[16]; uint4 u4[2]; } o;
#pragma unroll
            for (int j = 0; j < 4; ++j) {
                o.h[j] = (f16)v0[j]; o.h[4 + j] = (f16)v1[j];
                o.h[8 + j] = (f16)v2[j]; o.h[12 + j] = (f16)v3[j];
            }
            *(uint4*)&S[row][col] = o.u4[0];
            *(uint4*)&S[row][col + 8] = o.u4[1];
            f16* yd = Y16 + (size_t)(b * LK + m0 + row) * DIM + d0 + col;
            *(uint4*)yd = o.u4[0];          // 16 thr x 32B = 512B/row contiguous
            *(uint4*)(yd + 8) = o.u4[1];
        }
        __syncthreads();
        // transpose out: thread -> (d = t>>1, m-half = (t&1)*128); 256B/thread
        const int d = t >> 1, ms = (t & 1) * 128;
        f16* dst = YT + (size_t)(b * DIM + d0 + d) * LK + m0 + ms;
#pragma unroll
        for (int g = 0; g < 16; ++g) {
            union { f16 h[8]; uint4 u4; } o;
#pragma unroll
            for (int e = 0; e < 8; ++e) o.h[e] = S[ms + g * 8 + e][d];
            *(uint4*)(dst + g * 8) = o.u4;  // 2 thr x 256B = 512B/row
        }
        return;
    }
    if (bid < 1280) {  // ---- X convert: batch 8 loads, then 4 stores ----
        const size_t base = (size_t)(bid - 256) * 16384;
        floatx4 A[4], B[4];
#pragma unroll
        for (int kk = 0; kk < 4; ++kk) {
            size_t i = base + (size_t)(kk * 512 + t) * 8;
            A[kk] = *(const floatx4*)(ix + i);
            B[kk] = *(const floatx4*)(ix + i + 4);
        }
#pragma unroll
        for (int kk = 0; kk < 4; ++kk) {
            size_t i = base + (size_t)(kk * 512 + t) * 8;
            f16x8 o;
            o[0] = (f16)A[kk][0]; o[1] = (f16)A[kk][1];
            o[2] = (f16)A[kk][2]; o[3] = (f16)A[kk][3];
            o[4] = (f16)B[kk][0]; o[5] = (f16)B[kk][1];
            o[6] = (f16)B[kk][2]; o[7] = (f16)B[kk][3];
            *(f16x8*)(X16 + i) = o;
        }
        return;
    }
    if (bid < 1408) {  // ---- W transpose: 64e x 128d tiles ----
        f16(*S2)[136] = (f16(*)[136])Sraw;
        const int wtb = bid - 1280;
        const int e0 = (wtb & 15) * 64, d0 = (wtb >> 4) * 128;
        {
            int row = t >> 3, col = (t & 7) * 16;
            const float* src = W + (size_t)(e0 + row) * DIM + d0 + col;
            floatx4 v0 = *(const floatx4*)(src);
            floatx4 v1 = *(const floatx4*)(src + 4);
            floatx4 v2 = *(const floatx4*)(src + 8);
            floatx4 v3 = *(const floatx4*)(src + 12);
            union { f16 h[16]; uint4 u4[2]; } o;
#pragma unroll
            for (int j = 0; j < 4; ++j) {
                o.h[j] = (f16)v0[j]; o.h[4 + j] = (f16)v1[j];
                o.h[8 + j] = (f16)v2[j]; o.h[12 + j] = (f16)v3[j];
            }
            *(uint4*)&S2[row][col] = o.u4[0];
            *(uint4*)&S2[row][col + 8] = o.u4[1];
        }
        __syncthreads();
        const int d = t >> 2, ms = (t & 3) * 16;
        union { f16 h[16]; uint4 u4[2]; } o;
#pragma unroll
        for (int j = 0; j < 16; ++j) o.h[j] = S2[ms + j][d];
        f16* dst = WT + (size_t)(d0 + d) * DIM + e0 + ms;
        *(uint4*)dst = o.u4[0];
        *(uint4*)(dst + 8) = o.u4[1];
        return;
    }
    // ---- bias-projection partials: 8 super-chunks of 128 e ----
    {
        float* red = (float*)Sraw;  // float[512]
        const int pidx = bid - 1408;
        const int dd = t & 63, eg = t >> 6;
        const int d = (pidx & 15) * 64 + dd;
        const int es = pidx >> 4;
        const int e0 = es * 128 + eg * 16;
        float s = 0.f;
#pragma unroll
        for (int i = 0; i < 16; ++i)
            s += W[(size_t)(e0 + i) * DIM + d] * bias[e0 + i];
        red[t] = s;
        __syncthreads();
        if (eg == 0) {
            float acc = 0.f;
#pragma unroll
            for (int j = 0; j < 8; ++j) acc += red[dd + 64 * j];
            partial[es * DIM + d] = acc;
        }
    }
}

// ===========================================================================
// K_prep basic (fallback, 86MB layout — no YT; 16-chunk partial):
// ===========================================================================
__global__ __launch_bounds__(256) void k_prep_b(const float* __restrict__ ix,
                                                const float* __restrict__ io,
                                                const float* __restrict__ W,
                                                const float* __restrict__ bias,
                                                f16* __restrict__ X16,
                                                f16* __restrict__ Y16,
                                                f16* __restrict__ WT,
                                                float* __restrict__ partial) {
    __shared__ __align__(16) f16 S[64][72];
    const int bid = blockIdx.x;
    const int t = threadIdx.x;
    if (bid < 4096) {
        const float* src = (bid < 2048) ? ix : io;
        f16* dst = (bid < 2048) ? X16 : Y16;
        int bb = bid & 2047;
#pragma unroll
        for (int k = 0; k < 4; ++k) {
            size_t i = ((size_t)bb * 1024 + k * 256 + t) * 8;
            floatx4 a = *(const floatx4*)(src + i);
            floatx4 b = *(const floatx4*)(src + i + 4);
            f16x8 o;
            o[0] = (f16)a[0]; o[1] = (f16)a[1]; o[2] = (f16)a[2]; o[3] = (f16)a[3];
            o[4] = (f16)b[0]; o[5] = (f16)b[1]; o[6] = (f16)b[2]; o[7] = (f16)b[3];
            *(f16x8*)(dst + i) = o;
        }
        return;
    }
    if (bid < 4352) {
        const int wtb = bid - 4096;
        const int e0 = (wtb & 15) * 64, d0 = (wtb >> 4) * 64;
        {
            int row = t >> 2, cg = (t & 3) * 16;
            const float* src = W + (size_t)(e0 + row) * DIM + d0 + cg;
#pragma unroll
            for (int h = 0; h < 4; ++h) {
                floatx4 v = *(const floatx4*)(src + h * 4);
                f16x4 o;
                o[0] = (f16)v[0]; o[1] = (f16)v[1]; o[2] = (f16)v[2]; o[3] = (f16)v[3];
                *(f16x4*)&S[row][cg + h * 4] = o;
            }
        }
        __syncthreads();
        int dd = t >> 2, ms = (t & 3) * 16;
        union { f16 h[16]; uint4 u[2]; } o;
#pragma unroll
        for (int j = 0; j < 16; ++j) o.h[j] = S[ms + j][dd];
        f16* dst = WT + (size_t)(d0 + dd) * DIM + e0 + ms;
        *(uint4*)dst = o.u[0];
        *(uint4*)(dst + 8) = o.u[1];
        return;
    }
    {
        float* red = (float*)&S[0][0];
        const int idx = bid - 4352;
        int dd = t & 63, eg = t >> 6;
        int d = (idx & 15) * 64 + dd;
        int e0 = (idx >> 4) * 64 + eg * 16;
        float s = 0.f;
#pragma unroll
        for (int i = 0; i < 16; ++i)
            s += W[(size_t)(e0 + i) * DIM + d] * bias[e0 + i];
        red[t] = s;
        __syncthreads();
        if (eg == 0)
            partial[(idx >> 4) * DIM + d] =
                red[dd] + red[64 + dd] + red[128 + dd] + red[192 + dd];
    }
}

// K_yT (fallback only): pure transpose Y16 -> YT. grid (32,8,16).
__global__ __launch_bounds__(256) void k_ytrans(const f16* __restrict__ Y16,
                                                f16* __restrict__ YT) {
    __shared__ __align__(16) f16 S[64][72];
    const int b = blockIdx.x, m0 = blockIdx.y * 64, d0 = blockIdx.z * 64;
    const int t = threadIdx.x;
    {
        int row = t >> 2, cg = (t & 3) * 16;
        const f16* src = Y16 + (size_t)(b * LK + m0 + row) * DIM + d0 + cg;
        *(uint4*)&S[row][cg] = *(const uint4*)src;
        *(uint4*)&S[row][cg + 8] = *(const uint4*)(src + 8);
    }
    __syncthreads();
    int dd = t >> 2, ms = (t & 3) * 16;
    union { f16 h[16]; uint4 u[2]; } o;
#pragma unroll
    for (int j = 0; j < 16; ++j) o.h[j] = S[ms + j][dd];
    f16* dst = YT + (size_t)(b * DIM + d0 + dd) * LK + m0 + ms;
    *(uint4*)dst = o.u[0];
    *(uint4*)(dst + 8) = o.u[1];
}

// ===========================================================================
// K1: gram (64 blocks) + z (256 blocks) in one launch. nch = # partial chunks.
// ===========================================================================
__global__ __launch_bounds__(256) void k_gram_z(const f16* __restrict__ WT,
                                                const float* __restrict__ partial,
                                                const f16* __restrict__ Y16,
                                                f16* __restrict__ Gh,
                                                float* __restrict__ z,
                                                int nch) {
    __shared__ __align__(16) f16 sA[2][128 * 32];
    __shared__ __align__(16) f16 sB[2][128 * 32];
    __shared__ float cL[DIM];
    __shared__ float red[4][64];
    const int t = threadIdx.x;
    if (blockIdx.x >= 64) {  // ---- z block: 64 rows each ----
        const int idx = blockIdx.x - 64;
        const int lane = t & 63, w = t >> 6;
#pragma unroll
        for (int j = 0; j < 4; ++j) {
            int d = j * 256 + t;
            float s = 0.f;
            for (int k = 0; k < nch; ++k) s += partial[k * DIM + d];
            cL[d] = s;
        }
        __syncthreads();
        const int row = idx * 64 + lane;
        const f16* yr = Y16 + (size_t)row * DIM + w * 256;
        float s = 0.f;
#pragma unroll
        for (int c8 = 0; c8 < 256; c8 += 8) {
            f16x8 v = *(const f16x8*)(yr + c8);
#pragma unroll
            for (int j = 0; j < 8; ++j) s += (float)v[j] * cL[w * 256 + c8 + j];
        }
        red[w][lane] = s;
        __syncthreads();
        if (w == 0)
            z[row] = red[0][lane] + red[1][lane] + red[2][lane] + red[3][lane];
        return;
    }
    // ---- gram block ----
    const int lane = t & 63, wid = t >> 6;
    const int ln15 = lane & 15, q = lane >> 4;
    const int wr = (wid >> 1) * 64, wc = (wid & 1) * 64;
    const int i0 = (blockIdx.x >> 3) * 128, j0 = (blockIdx.x & 7) * 128;
    floatx4 acc[4][4] = {};

    const int srow = t >> 2, scol = (t & 3) * 8;
    const f16* gA = WT + (size_t)(i0 + srow) * DIM + scol;
    const f16* gB = WT + (size_t)(j0 + srow) * DIM + scol;

    auto stage = [&](int buf, int e0) {
#pragma unroll
        for (int is = 0; is < 2; ++is) {
            glds16(gA + (size_t)(is * 64) * DIM + e0,
                   (char*)&sA[buf][0] + is * 4096 + t * 16);
            glds16(gB + (size_t)(is * 64) * DIM + e0,
                   (char*)&sB[buf][0] + is * 4096 + t * 16);
        }
    };
    auto compute = [&](int buf) {
        f16x8 a[4];
#pragma unroll
        for (int mi = 0; mi < 4; ++mi)
            a[mi] = *(const f16x8*)&sA[buf][(wr + mi * 16 + ln15) * 32 + q * 8];
#pragma unroll
        for (int ni = 0; ni < 4; ++ni) {
            f16x8 bv = *(const f16x8*)&sB[buf][(wc + ni * 16 + ln15) * 32 + q * 8];
#pragma unroll
            for (int mi = 0; mi < 4; ++mi)
                acc[mi][ni] = MFMA16(a[mi], bv, acc[mi][ni]);
        }
    };

    stage(0, 0);
    stage(1, 32);
    for (int tt = 0; tt < 32; ++tt) {
        if (tt < 31) { WAITVM(4); } else { WAITVM(0); }
        BARRIER();
        CFENCE();
        __builtin_amdgcn_s_setprio(1);
        compute(tt & 1);
        __builtin_amdgcn_s_setprio(0);
        CFENCE();
        BARRIER();
        if (tt < 30) stage(tt & 1, (tt + 2) * 32);
    }

#pragma unroll
    for (int mi = 0; mi < 4; ++mi)
#pragma unroll
        for (int ni = 0; ni < 4; ++ni)
#pragma unroll
            for (int r = 0; r < 4; ++r)
                Gh[(size_t)(i0 + wr + mi * 16 + q * 4 + r) * DIM +
                   j0 + wc + ni * 16 + ln15] = (f16)acc[mi][ni][r];
}

// ===========================================================================
// K2: Th = fp16(X16 @ Gh). Proven r2 config: 128x128, 2-buf 32KB, 4 blk/CU.
// ===========================================================================
__global__ __launch_bounds__(256) void k_tgemm(const f16* __restrict__ X16,
                                               const f16* __restrict__ Gh,
                                               f16* __restrict__ Th) {
    __shared__ __align__(16) f16 sA[2][128 * 32];
    __shared__ __align__(16) f16 sB[2][128 * 32];
    const int t = threadIdx.x;
    const int lane = t & 63, wid = t >> 6;
    const int ln15 = lane & 15, q = lane >> 4;
    const int wr = (wid >> 1) * 64, wc = (wid & 1) * 64;
    const int m0 = blockIdx.x * 128, n0 = blockIdx.y * 128;
    floatx4 acc[4][4] = {};

    const int srow = t >> 2, scol = (t & 3) * 8;
    const f16* gA = X16 + (size_t)(m0 + srow) * DIM + scol;
    const f16* gB = Gh + (size_t)(n0 + srow) * DIM + scol;

    auto stage = [&](int buf, int e0) {
#pragma unroll
        for (int is = 0; is < 2; ++is) {
            glds16(gA + (size_t)(is * 64) * DIM + e0,
                   (char*)&sA[buf][0] + is * 4096 + t * 16);
            glds16(gB + (size_t)(is * 64) * DIM + e0,
                   (char*)&sB[buf][0] + is * 4096 + t * 16);
        }
    };
    auto compute = [&](int buf) {
        f16x8 a[4];
#pragma unroll
        for (int mi = 0; mi < 4; ++mi)
            a[mi] = *(const f16x8*)&sA[buf][(wr + mi * 16 + ln15) * 32 + q * 8];
#pragma unroll
        for (int ni = 0; ni < 4; ++ni) {
            f16x8 bv = *(const f16x8*)&sB[buf][(wc + ni * 16 + ln15) * 32 + q * 8];
#pragma unroll
            for (int mi = 0; mi < 4; ++mi)
                acc[mi][ni] = MFMA16(a[mi], bv, acc[mi][ni]);
        }
    };

    stage(0, 0);
    stage(1, 32);
    for (int tt = 0; tt < 32; ++tt) {
        if (tt < 31) { WAITVM(4); } else { WAITVM(0); }
        BARRIER();
        CFENCE();
        __builtin_amdgcn_s_setprio(1);
        compute(tt & 1);
        __builtin_amdgcn_s_setprio(0);
        CFENCE();
        BARRIER();
        if (tt < 30) stage(tt & 1, (tt + 2) * 32);
    }

#pragma unroll
    for (int mi = 0; mi < 4; ++mi)
#pragma unroll
        for (int ni = 0; ni < 4; ++ni)
#pragma unroll
            for (int r = 0; r < 4; ++r)
                Th[(size_t)(m0 + wr + mi * 16 + q * 4 + r) * DIM +
                   n0 + wc + ni * 16 + ln15] = (f16)acc[mi][ni][r];
}

// ===========================================================================
// K3: QK^T + softmax -> P, Lsum. XCD batch-affinity; now 4-buffer 1-barrier
// counted-vmcnt (3 tiles in flight; LDS 148KB, still 1 block/CU).
// ===========================================================================
__global__ __launch_bounds__(512) void k_attn(const f16* __restrict__ Th,
                                              const f16* __restrict__ Y16,
                                              const float* __restrict__ Z,
                                              f16* __restrict__ P,
                                              float* __restrict__ Lsum) {
    __shared__ __align__(16) f16 sS[4][18432];  // 4 x 36864 B
    __shared__ float redmax[64][8];
    __shared__ float redsum[64][8];
    const int g = blockIdx.x;
    const int b = (g & 7) + 8 * (g >> 6);
    const int l0 = ((g >> 3) & 7) * 64;
    const int t = threadIdx.x;
    const int lane = t & 63, w = t >> 6;
    const int ln15 = lane & 15, q = lane >> 4;
    const bool heavy = (t < 256);  // waves 0-3 issue 5 glds/tile
    floatx4 acc[4][4] = {};

    auto stage = [&](int buf, int e0) {
#pragma unroll
        for (int is = 0; is < 4; ++is) {
            int ff = is * 8192 + t * 16;
            const f16* g2;
            if (ff < 4096) {
                g2 = Th + (size_t)(b * LQ + l0 + (ff >> 6)) * DIM + e0 + ((ff & 63) >> 1);
            } else {
                int f2 = ff - 4096;
                g2 = Y16 + (size_t)(b * LK + (f2 >> 6)) * DIM + e0 + ((f2 & 63) >> 1);
            }
            glds16(g2, (char*)&sS[buf][0] + ff);
        }
        if (heavy) {
            int ff = 32768 + t * 16;
            int f2 = ff - 4096;
            const f16* g2 = Y16 + (size_t)(b * LK + (f2 >> 6)) * DIM + e0 + ((f2 & 63) >> 1);
            glds16(g2, (char*)&sS[buf][0] + ff);
        }
    };
    auto compute = [&](int buf) {
        f16x8 th[4];
#pragma unroll
        for (int mi = 0; mi < 4; ++mi)
            th[mi] = *(const f16x8*)&sS[buf][(mi * 16 + ln15) * 32 + q * 8];
#pragma unroll
        for (int ni = 0; ni < 4; ++ni) {
            f16x8 y = *(const f16x8*)&sS[buf][2048 + (w * 64 + ni * 16 + ln15) * 32 + q * 8];
#pragma unroll
            for (int mi = 0; mi < 4; ++mi)
                acc[mi][ni] = MFMA16(th[mi], y, acc[mi][ni]);
        }
    };

    stage(0, 0);
    stage(1, 32);
    stage(2, 64);
    int cur = 0;
    for (int tt = 0; tt < 32; ++tt) {
        // drain tile tt; up to 2 further stages stay in flight
        if (tt < 30) {
            if (heavy) { WAITVM(10); } else { WAITVM(8); }
        } else if (tt == 30) {
            if (heavy) { WAITVM(5); } else { WAITVM(4); }
        } else {
            WAITVM(0);
        }
        BARRIER();
        CFENCE();
        if (tt < 29) stage((cur + 3) & 3, (tt + 3) * 32);
        __builtin_amdgcn_s_setprio(1);
        compute(cur);
        __builtin_amdgcn_s_setprio(0);
        CFENCE();
        cur = (cur + 1) & 3;
    }

    float zv[4];
#pragma unroll
    for (int ni = 0; ni < 4; ++ni) zv[ni] = Z[b * LK + w * 64 + ni * 16 + ln15];

    float rmx[4][4];
#pragma unroll
    for (int mi = 0; mi < 4; ++mi)
#pragma unroll
        for (int r = 0; r < 4; ++r) {
            float m = -3.0e38f;
#pragma unroll
            for (int ni = 0; ni < 4; ++ni) m = fmaxf(m, acc[mi][ni][r] + zv[ni]);
#pragma unroll
            for (int off = 1; off < 16; off <<= 1) m = fmaxf(m, __shfl_xor(m, off, 64));
            rmx[mi][r] = m;
        }
    if (ln15 == 0) {
#pragma unroll
        for (int mi = 0; mi < 4; ++mi)
#pragma unroll
            for (int r = 0; r < 4; ++r) redmax[mi * 16 + q * 4 + r][w] = rmx[mi][r];
    }
    __syncthreads();
#pragma unroll
    for (int mi = 0; mi < 4; ++mi)
#pragma unroll
        for (int r = 0; r < 4; ++r) {
            int row = mi * 16 + q * 4 + r;
            float m = redmax[row][0];
#pragma unroll
            for (int j = 1; j < 8; ++j) m = fmaxf(m, redmax[row][j]);
            rmx[mi][r] = m;
        }
    float rsm[4][4] = {};
#pragma unroll
    for (int mi = 0; mi < 4; ++mi)
#pragma unroll
        for (int ni = 0; ni < 4; ++ni)
#pragma unroll
            for (int r = 0; r < 4; ++r) {
                float e = __expf(acc[mi][ni][r] + zv[ni] - rmx[mi][r]);
                acc[mi][ni][r] = e;
                rsm[mi][r] += e;
            }
#pragma unroll
    for (int mi = 0; mi < 4; ++mi)
#pragma unroll
        for (int r = 0; r < 4; ++r) {
            float s = rsm[mi][r];
#pragma unroll
            for (int off = 1; off < 16; off <<= 1) s += __shfl_xor(s, off, 64);
            rsm[mi][r] = s;
        }
    if (ln15 == 0) {
#pragma unroll
        for (int mi = 0; mi < 4; ++mi)
#pragma unroll
            for (int r = 0; r < 4; ++r) redsum[mi * 16 + q * 4 + r][w] = rsm[mi][r];
    }
    __syncthreads();
    if (w == 0 && ln15 == 0) {
#pragma unroll
        for (int mi = 0; mi < 4; ++mi)
#pragma unroll
            for (int r = 0; r < 4; ++r) {
                int row = mi * 16 + q * 4 + r;
                float s = 0.f;
#pragma unroll
                for (int j = 0; j < 8; ++j) s += redsum[row][j];
                Lsum[b * LQ + l0 + row] = s;
            }
    }
#pragma unroll
    for (int mi = 0; mi < 4; ++mi)
#pragma unroll
        for (int ni = 0; ni < 4; ++ni)
#pragma unroll
            for (int r = 0; r < 4; ++r) {
                int row = l0 + mi * 16 + q * 4 + r;
                int col = w * 64 + ni * 16 + ln15;
                P[(size_t)(b * LQ + row) * LK + col] = (f16)acc[mi][ni][r];
            }
}

// ===========================================================================
// K4: O = (P @ y) / Lsum via YT. r8 form (2-buf 32KB, XCD batch-affinity).
// ===========================================================================
__global__ __launch_bounds__(256) void k_pv(const f16* __restrict__ P,
                                            const f16* __restrict__ YT,
                                            const float* __restrict__ Lsum,
                                            float* __restrict__ O) {
    __shared__ __align__(16) f16 sA[2][128 * 32];
    __shared__ __align__(16) f16 sB[2][128 * 32];
    const int t = threadIdx.x;
    const int lane = t & 63, wid = t >> 6;
    const int ln15 = lane & 15, q = lane >> 4;
    const int wr = (wid >> 1) * 64, wc = (wid & 1) * 64;
    const int g = blockIdx.x;
    const int b = (g & 7) + 8 * (g >> 8);
    const int inner = (g >> 3) & 31;
    const int m0 = (inner >> 3) * 128, n0 = (inner & 7) * 128;
    floatx4 acc[4][4] = {};

    const int srow = t >> 2, scol = (t & 3) * 8;
    const f16* gA = P + (size_t)(b * LQ + m0 + srow) * LK + scol;
    const f16* gB = YT + (size_t)(b * DIM + n0 + srow) * LK + scol;

    auto stage = [&](int buf, int k0) {
#pragma unroll
        for (int is = 0; is < 2; ++is) {
            glds16(gA + (size_t)(is * 64) * LK + k0,
                   (char*)&sA[buf][0] + is * 4096 + t * 16);
            glds16(gB + (size_t)(is * 64) * LK + k0,
                   (char*)&sB[buf][0] + is * 4096 + t * 16);
        }
    };
    auto compute = [&](int buf) {
        f16x8 a[4];
#pragma unroll
        for (int mi = 0; mi < 4; ++mi)
            a[mi] = *(const f16x8*)&sA[buf][(wr + mi * 16 + ln15) * 32 + q * 8];
#pragma unroll
        for (int ni = 0; ni < 4; ++ni) {
            f16x8 bv = *(const f16x8*)&sB[buf][(wc + ni * 16 + ln15) * 32 + q * 8];
#pragma unroll
            for (int mi = 0; mi < 4; ++mi) acc[mi][ni] = MFMA16(a[mi], bv, acc[mi][ni]);
        }
    };

    stage(0, 0);
    stage(1, 32);
    for (int tt = 0; tt < 16; ++tt) {
        if (tt < 15) { WAITVM(4); } else { WAITVM(0); }
        BARRIER();
        CFENCE();
        __builtin_amdgcn_s_setprio(1);
        compute(tt & 1);
        __builtin_amdgcn_s_setprio(0);
        CFENCE();
        BARRIER();
        if (tt < 14) stage(tt & 1, (tt + 2) * 32);
    }

    float invl[4][4];
#pragma unroll
    for (int mi = 0; mi < 4; ++mi)
#pragma unroll
        for (int r = 0; r < 4; ++r)
            invl[mi][r] = 1.0f / Lsum[b * LQ + m0 + wr + mi * 16 + q * 4 + r];
#pragma unroll
    for (int mi = 0; mi < 4; ++mi)
#pragma unroll
        for (int ni = 0; ni < 4; ++ni)
#pragma unroll
            for (int r = 0; r < 4; ++r)
                O[(size_t)(b * LQ + m0 + wr + mi * 16 + q * 4 + r) * DIM +
                  n0 + wc + ni * 16 + ln15] = acc[mi][ni][r] * invl[mi][r];
}

// ---------------------------------------------------------------------------
// FUSED (~100.2 MB): X16@0 (P@0 after it dies), Y16@32M, YT@64M, Gh@96M,
//   WT@98M, partial/z/L tail. 5 launches.
// BASIC (86.2 MB): r7 layout, 6 launches.
// ---------------------------------------------------------------------------
extern "C" void kernel_launch(void* const* d_in, const int* in_sizes, int n_in,
                              void* d_out, int out_size, void* d_ws, size_t ws_size,
                              hipStream_t stream) {
    const float* ix = (const float*)d_in[0];
    const float* io = (const float*)d_in[1];
    const float* W = (const float*)d_in[2];
    const float* bb = (const float*)d_in[3];
    float* out = (float*)d_out;
    char* ws = (char*)d_ws;
    f16* Th = (f16*)d_out;

    if (ws_size >= 105054208ull) {  // fused layout
        f16* X16 = (f16*)(ws);
        f16* P = (f16*)(ws);
        f16* Y16 = (f16*)(ws + 33554432);
        f16* YT = (f16*)(ws + 67108864);
        f16* Gh = (f16*)(ws + 100663296);
        f16* WT = (f16*)(ws + 102760448);
        float* partial = (float*)(ws + 104857600);
        float* z = (float*)(ws + 104923136);
        float* L = (float*)(ws + 104988672);

        k_prep_f<<<dim3(1536), dim3(512), 0, stream>>>(ix, io, W, bb, X16, Y16,
                                                       YT, WT, partial);
        k_gram_z<<<dim3(320), dim3(256), 0, stream>>>(WT, partial, Y16, Gh, z, 8);
        k_tgemm<<<dim3(128, 8), dim3(256), 0, stream>>>(X16, Gh, Th);
        k_attn<<<dim3(256), dim3(512), 0, stream>>>(Th, Y16, z, P, L);
        k_pv<<<dim3(1024), dim3(256), 0, stream>>>(P, YT, L, out);
    } else {  // basic layout
        f16* X16 = (f16*)(ws);
        f16* YT = (f16*)(ws);
        f16* Y16 = (f16*)(ws + 33554432);
        f16* P = (f16*)(ws + 67108864);
        f16* WT = (f16*)(ws + 67108864);
        f16* Gh = (f16*)(ws + 83886080);
        float* z = (float*)(ws + 85987328);
        float* L = (float*)(ws + 86052864);
        float* partial = (float*)(ws + 86118400);

        k_prep_b<<<dim3(4608), dim3(256), 0, stream>>>(ix, io, W, bb, X16, Y16,
                                                       WT, partial);
        k_gram_z<<<dim3(320), dim3(256), 0, stream>>>(WT, partial, Y16, Gh, z, 16);
        k_tgemm<<<dim3(128, 8), dim3(256), 0, stream>>>(X16, Gh, Th);
        k_ytrans<<<dim3(32, 8, 16), dim3(256), 0, stream>>>(Y16, YT);
        k_attn<<<dim3(256), dim3(512), 0, stream>>>(Th, Y16, z, P, L);
        k_pv<<<dim3(1024), dim3(256), 0, stream>>>(P, YT, L, out);
    }
}

// Round 10
// 320.446 us; speedup vs baseline: 1.0095x; 1.0095x over previous
//
#include <hip/hip_runtime.h>

typedef _Float16 f16;
typedef __attribute__((ext_vector_type(8))) _Float16 f16x8;
typedef __attribute__((ext_vector_type(4))) _Float16 f16x4;
typedef __attribute__((ext_vector_type(4))) float floatx4;

#define MFMA16(a, b, c) __builtin_amdgcn_mfma_f32_16x16x32_f16(a, b, c, 0, 0, 0)

#define BATCH 32
#define LQ 512
#define LK 512
#define DIM 1024

#define BARRIER() __builtin_amdgcn_s_barrier()
#define CFENCE() asm volatile("" ::: "memory")
#define WAITVM(n) asm volatile("s_waitcnt vmcnt(" #n ")" ::: "memory")

// async global->LDS, 16B per lane. Lessons: r4 — never pre-swizzle the global
// source (breaks coalescing); r3/r6/r9 — LDS size gates occupancy for the
// WHOLE kernel (all branches), keep GEMM LDS at 32KB and prep LDS at 32KB.
__device__ __forceinline__ void glds16(const void* g, void* l) {
    __builtin_amdgcn_global_load_lds(
        (const __attribute__((address_space(1))) unsigned int*)g,
        (__attribute__((address_space(3))) unsigned int*)l, 16, 0, 0);
}

// ===========================================================================
// K_prep fused, 512 thr, 2304 blocks, 32KB LDS -> 4 blocks/CU (wave-capped,
// 100% occ). r9 lesson: 132KB LDS capped everything at 1 block/CU.
//   bid [0,1024):     io 64x256 tiles -> Y16 (512B row segs) + YT
//                     (LDS gather is conflict-free: m wave-uniform per read,
//                      d lane-linear; YT writes 64B/thread = full lines)
//   bid [1024,2048):  X16 = fp16(ix), 8 loads in flight
//   bid [2048,2176):  WT 64e x 128d transpose tiles
//   bid [2176,2304):  partial[es][d] = sum_{e in 128-chunk} W[e][d]*bias[e]
// ===========================================================================
__global__ __launch_bounds__(512) void k_prep_f(const float* __restrict__ ix,
                                                const float* __restrict__ io,
                                                const float* __restrict__ W,
                                                const float* __restrict__ bias,
                                                f16* __restrict__ X16,
                                                f16* __restrict__ Y16,
                                                f16* __restrict__ YT,
                                                f16* __restrict__ WT,
                                                float* __restrict__ partial) {
    __shared__ __align__(16) char Sraw[32768];
    const int bid = blockIdx.x;
    const int t = threadIdx.x;
    if (bid < 1024) {  // ---- io 64x256 tile: fp32 -> Y16 (row) + YT (col) ----
        f16(*S)[256] = (f16(*)[256])Sraw;
        const int b = bid >> 5;
        const int m0 = ((bid >> 2) & 7) * 64, d0 = (bid & 3) * 256;
        const int row_t = t >> 4, col = (t & 15) * 16;
#pragma unroll
        for (int u = 0; u < 2; ++u) {
            int row = u * 32 + row_t;
            const float* src = io + (size_t)(b * LK + m0 + row) * DIM + d0 + col;
            floatx4 v0 = *(const floatx4*)(src);
            floatx4 v1 = *(const floatx4*)(src + 4);
            floatx4 v2 = *(const floatx4*)(src + 8);
            floatx4 v3 = *(const floatx4*)(src + 12);
            union { f16 h[16]; uint4 u4[2]; } o;
#pragma unroll
            for (int j = 0; j < 4; ++j) {
                o.h[j] = (f16)v0[j]; o.h[4 + j] = (f16)v1[j];
                o.h[8 + j] = (f16)v2[j]; o.h[12 + j] = (f16)v3[j];
            }
            *(uint4*)&S[row][col] = o.u4[0];
            *(uint4*)&S[row][col + 8] = o.u4[1];
            f16* yd = Y16 + (size_t)(b * LK + m0 + row) * DIM + d0 + col;
            *(uint4*)yd = o.u4[0];          // 16 thr x 32B = 512B/row contiguous
            *(uint4*)(yd + 8) = o.u4[1];
        }
        __syncthreads();
        // gather: d = t&255 (lane-linear), m wave-uniform per iteration
        const int d = t & 255, mp = (t >> 8) * 32;
        union { f16 h[32]; uint4 u4[4]; } o;
#pragma unroll
        for (int e = 0; e < 32; ++e) o.h[e] = S[mp + e][d];
        f16* dst = YT + (size_t)(b * DIM + d0 + d) * LK + m0 + mp;
        *(uint4*)dst = o.u4[0];
        *(uint4*)(dst + 8) = o.u4[1];
        *(uint4*)(dst + 16) = o.u4[2];
        *(uint4*)(dst + 24) = o.u4[3];
        return;
    }
    if (bid < 2048) {  // ---- X convert: batch 8 loads, then 4 stores ----
        const size_t base = (size_t)(bid - 1024) * 16384;
        floatx4 A[4], B[4];
#pragma unroll
        for (int kk = 0; kk < 4; ++kk) {
            size_t i = base + (size_t)(kk * 512 + t) * 8;
            A[kk] = *(const floatx4*)(ix + i);
            B[kk] = *(const floatx4*)(ix + i + 4);
        }
#pragma unroll
        for (int kk = 0; kk < 4; ++kk) {
            size_t i = base + (size_t)(kk * 512 + t) * 8;
            f16x8 o;
            o[0] = (f16)A[kk][0]; o[1] = (f16)A[kk][1];
            o[2] = (f16)A[kk][2]; o[3] = (f16)A[kk][3];
            o[4] = (f16)B[kk][0]; o[5] = (f16)B[kk][1];
            o[6] = (f16)B[kk][2]; o[7] = (f16)B[kk][3];
            *(f16x8*)(X16 + i) = o;
        }
        return;
    }
    if (bid < 2176) {  // ---- W transpose: 64e x 128d tiles ----
        f16(*S2)[136] = (f16(*)[136])Sraw;
        const int wtb = bid - 2048;
        const int e0 = (wtb & 15) * 64, d0 = (wtb >> 4) * 128;
        {
            int row = t >> 3, col = (t & 7) * 16;
            const float* src = W + (size_t)(e0 + row) * DIM + d0 + col;
            floatx4 v0 = *(const floatx4*)(src);
            floatx4 v1 = *(const floatx4*)(src + 4);
            floatx4 v2 = *(const floatx4*)(src + 8);
            floatx4 v3 = *(const floatx4*)(src + 12);
            union { f16 h[16]; uint4 u4[2]; } o;
#pragma unroll
            for (int j = 0; j < 4; ++j) {
                o.h[j] = (f16)v0[j]; o.h[4 + j] = (f16)v1[j];
                o.h[8 + j] = (f16)v2[j]; o.h[12 + j] = (f16)v3[j];
            }
            *(uint4*)&S2[row][col] = o.u4[0];
            *(uint4*)&S2[row][col + 8] = o.u4[1];
        }
        __syncthreads();
        const int d = t >> 2, ms = (t & 3) * 16;
        union { f16 h[16]; uint4 u4[2]; } o;
#pragma unroll
        for (int j = 0; j < 16; ++j) o.h[j] = S2[ms + j][d];
        f16* dst = WT + (size_t)(d0 + d) * DIM + e0 + ms;
        *(uint4*)dst = o.u4[0];
        *(uint4*)(dst + 8) = o.u4[1];
        return;
    }
    // ---- bias-projection partials: 8 super-chunks of 128 e ----
    {
        float* red = (float*)Sraw;  // float[512]
        const int pidx = bid - 2176;
        const int dd = t & 63, eg = t >> 6;
        const int d = (pidx & 15) * 64 + dd;
        const int es = pidx >> 4;
        const int e0 = es * 128 + eg * 16;
        float s = 0.f;
#pragma unroll
        for (int i = 0; i < 16; ++i)
            s += W[(size_t)(e0 + i) * DIM + d] * bias[e0 + i];
        red[t] = s;
        __syncthreads();
        if (eg == 0) {
            float acc = 0.f;
#pragma unroll
            for (int j = 0; j < 8; ++j) acc += red[dd + 64 * j];
            partial[es * DIM + d] = acc;
        }
    }
}

// ===========================================================================
// K_prep basic (fallback, 86MB layout — no YT; 16-chunk partial):
// ===========================================================================
__global__ __launch_bounds__(256) void k_prep_b(const float* __restrict__ ix,
                                                const float* __restrict__ io,
                                                const float* __restrict__ W,
                                                const float* __restrict__ bias,
                                                f16* __restrict__ X16,
                                                f16* __restrict__ Y16,
                                                f16* __restrict__ WT,
                                                float* __restrict__ partial) {
    __shared__ __align__(16) f16 S[64][72];
    const int bid = blockIdx.x;
    const int t = threadIdx.x;
    if (bid < 4096) {
        const float* src = (bid < 2048) ? ix : io;
        f16* dst = (bid < 2048) ? X16 : Y16;
        int bb = bid & 2047;
#pragma unroll
        for (int k = 0; k < 4; ++k) {
            size_t i = ((size_t)bb * 1024 + k * 256 + t) * 8;
            floatx4 a = *(const floatx4*)(src + i);
            floatx4 b = *(const floatx4*)(src + i + 4);
            f16x8 o;
            o[0] = (f16)a[0]; o[1] = (f16)a[1]; o[2] = (f16)a[2]; o[3] = (f16)a[3];
            o[4] = (f16)b[0]; o[5] = (f16)b[1]; o[6] = (f16)b[2]; o[7] = (f16)b[3];
            *(f16x8*)(dst + i) = o;
        }
        return;
    }
    if (bid < 4352) {
        const int wtb = bid - 4096;
        const int e0 = (wtb & 15) * 64, d0 = (wtb >> 4) * 64;
        {
            int row = t >> 2, cg = (t & 3) * 16;
            const float* src = W + (size_t)(e0 + row) * DIM + d0 + cg;
#pragma unroll
            for (int h = 0; h < 4; ++h) {
                floatx4 v = *(const floatx4*)(src + h * 4);
                f16x4 o;
                o[0] = (f16)v[0]; o[1] = (f16)v[1]; o[2] = (f16)v[2]; o[3] = (f16)v[3];
                *(f16x4*)&S[row][cg + h * 4] = o;
            }
        }
        __syncthreads();
        int dd = t >> 2, ms = (t & 3) * 16;
        union { f16 h[16]; uint4 u[2]; } o;
#pragma unroll
        for (int j = 0; j < 16; ++j) o.h[j] = S[ms + j][dd];
        f16* dst = WT + (size_t)(d0 + dd) * DIM + e0 + ms;
        *(uint4*)dst = o.u[0];
        *(uint4*)(dst + 8) = o.u[1];
        return;
    }
    {
        float* red = (float*)&S[0][0];
        const int idx = bid - 4352;
        int dd = t & 63, eg = t >> 6;
        int d = (idx & 15) * 64 + dd;
        int e0 = (idx >> 4) * 64 + eg * 16;
        float s = 0.f;
#pragma unroll
        for (int i = 0; i < 16; ++i)
            s += W[(size_t)(e0 + i) * DIM + d] * bias[e0 + i];
        red[t] = s;
        __syncthreads();
        if (eg == 0)
            partial[(idx >> 4) * DIM + d] =
                red[dd] + red[64 + dd] + red[128 + dd] + red[192 + dd];
    }
}

// K_yT (fallback only): pure transpose Y16 -> YT. grid (32,8,16).
__global__ __launch_bounds__(256) void k_ytrans(const f16* __restrict__ Y16,
                                                f16* __restrict__ YT) {
    __shared__ __align__(16) f16 S[64][72];
    const int b = blockIdx.x, m0 = blockIdx.y * 64, d0 = blockIdx.z * 64;
    const int t = threadIdx.x;
    {
        int row = t >> 2, cg = (t & 3) * 16;
        const f16* src = Y16 + (size_t)(b * LK + m0 + row) * DIM + d0 + cg;
        *(uint4*)&S[row][cg] = *(const uint4*)src;
        *(uint4*)&S[row][cg + 8] = *(const uint4*)(src + 8);
    }
    __syncthreads();
    int dd = t >> 2, ms = (t & 3) * 16;
    union { f16 h[16]; uint4 u[2]; } o;
#pragma unroll
    for (int j = 0; j < 16; ++j) o.h[j] = S[ms + j][dd];
    f16* dst = YT + (size_t)(b * DIM + d0 + dd) * LK + m0 + ms;
    *(uint4*)dst = o.u[0];
    *(uint4*)(dst + 8) = o.u[1];
}

// ===========================================================================
// K1: gram (64 blocks) + z (256 blocks) in one launch. nch = # partial chunks.
// ===========================================================================
__global__ __launch_bounds__(256) void k_gram_z(const f16* __restrict__ WT,
                                                const float* __restrict__ partial,
                                                const f16* __restrict__ Y16,
                                                f16* __restrict__ Gh,
                                                float* __restrict__ z,
                                                int nch) {
    __shared__ __align__(16) f16 sA[2][128 * 32];
    __shared__ __align__(16) f16 sB[2][128 * 32];
    __shared__ float cL[DIM];
    __shared__ float red[4][64];
    const int t = threadIdx.x;
    if (blockIdx.x >= 64) {  // ---- z block: 64 rows each ----
        const int idx = blockIdx.x - 64;
        const int lane = t & 63, w = t >> 6;
#pragma unroll
        for (int j = 0; j < 4; ++j) {
            int d = j * 256 + t;
            float s = 0.f;
            for (int k = 0; k < nch; ++k) s += partial[k * DIM + d];
            cL[d] = s;
        }
        __syncthreads();
        const int row = idx * 64 + lane;
        const f16* yr = Y16 + (size_t)row * DIM + w * 256;
        float s = 0.f;
#pragma unroll
        for (int c8 = 0; c8 < 256; c8 += 8) {
            f16x8 v = *(const f16x8*)(yr + c8);
#pragma unroll
            for (int j = 0; j < 8; ++j) s += (float)v[j] * cL[w * 256 + c8 + j];
        }
        red[w][lane] = s;
        __syncthreads();
        if (w == 0)
            z[row] = red[0][lane] + red[1][lane] + red[2][lane] + red[3][lane];
        return;
    }
    // ---- gram block ----
    const int lane = t & 63, wid = t >> 6;
    const int ln15 = lane & 15, q = lane >> 4;
    const int wr = (wid >> 1) * 64, wc = (wid & 1) * 64;
    const int i0 = (blockIdx.x >> 3) * 128, j0 = (blockIdx.x & 7) * 128;
    floatx4 acc[4][4] = {};

    const int srow = t >> 2, scol = (t & 3) * 8;
    const f16* gA = WT + (size_t)(i0 + srow) * DIM + scol;
    const f16* gB = WT + (size_t)(j0 + srow) * DIM + scol;

    auto stage = [&](int buf, int e0) {
#pragma unroll
        for (int is = 0; is < 2; ++is) {
            glds16(gA + (size_t)(is * 64) * DIM + e0,
                   (char*)&sA[buf][0] + is * 4096 + t * 16);
            glds16(gB + (size_t)(is * 64) * DIM + e0,
                   (char*)&sB[buf][0] + is * 4096 + t * 16);
        }
    };
    auto compute = [&](int buf) {
        f16x8 a[4];
#pragma unroll
        for (int mi = 0; mi < 4; ++mi)
            a[mi] = *(const f16x8*)&sA[buf][(wr + mi * 16 + ln15) * 32 + q * 8];
#pragma unroll
        for (int ni = 0; ni < 4; ++ni) {
            f16x8 bv = *(const f16x8*)&sB[buf][(wc + ni * 16 + ln15) * 32 + q * 8];
#pragma unroll
            for (int mi = 0; mi < 4; ++mi)
                acc[mi][ni] = MFMA16(a[mi], bv, acc[mi][ni]);
        }
    };

    stage(0, 0);
    stage(1, 32);
    for (int tt = 0; tt < 32; ++tt) {
        if (tt < 31) { WAITVM(4); } else { WAITVM(0); }
        BARRIER();
        CFENCE();
        __builtin_amdgcn_s_setprio(1);
        compute(tt & 1);
        __builtin_amdgcn_s_setprio(0);
        CFENCE();
        BARRIER();
        if (tt < 30) stage(tt & 1, (tt + 2) * 32);
    }

#pragma unroll
    for (int mi = 0; mi < 4; ++mi)
#pragma unroll
        for (int ni = 0; ni < 4; ++ni)
#pragma unroll
            for (int r = 0; r < 4; ++r)
                Gh[(size_t)(i0 + wr + mi * 16 + q * 4 + r) * DIM +
                   j0 + wc + ni * 16 + ln15] = (f16)acc[mi][ni][r];
}

// ===========================================================================
// K2: Th = fp16(X16 @ Gh). Proven r2 config: 128x128, 2-buf 32KB, 4 blk/CU.
// ===========================================================================
__global__ __launch_bounds__(256) void k_tgemm(const f16* __restrict__ X16,
                                               const f16* __restrict__ Gh,
                                               f16* __restrict__ Th) {
    __shared__ __align__(16) f16 sA[2][128 * 32];
    __shared__ __align__(16) f16 sB[2][128 * 32];
    const int t = threadIdx.x;
    const int lane = t & 63, wid = t >> 6;
    const int ln15 = lane & 15, q = lane >> 4;
    const int wr = (wid >> 1) * 64, wc = (wid & 1) * 64;
    const int m0 = blockIdx.x * 128, n0 = blockIdx.y * 128;
    floatx4 acc[4][4] = {};

    const int srow = t >> 2, scol = (t & 3) * 8;
    const f16* gA = X16 + (size_t)(m0 + srow) * DIM + scol;
    const f16* gB = Gh + (size_t)(n0 + srow) * DIM + scol;

    auto stage = [&](int buf, int e0) {
#pragma unroll
        for (int is = 0; is < 2; ++is) {
            glds16(gA + (size_t)(is * 64) * DIM + e0,
                   (char*)&sA[buf][0] + is * 4096 + t * 16);
            glds16(gB + (size_t)(is * 64) * DIM + e0,
                   (char*)&sB[buf][0] + is * 4096 + t * 16);
        }
    };
    auto compute = [&](int buf) {
        f16x8 a[4];
#pragma unroll
        for (int mi = 0; mi < 4; ++mi)
            a[mi] = *(const f16x8*)&sA[buf][(wr + mi * 16 + ln15) * 32 + q * 8];
#pragma unroll
        for (int ni = 0; ni < 4; ++ni) {
            f16x8 bv = *(const f16x8*)&sB[buf][(wc + ni * 16 + ln15) * 32 + q * 8];
#pragma unroll
            for (int mi = 0; mi < 4; ++mi)
                acc[mi][ni] = MFMA16(a[mi], bv, acc[mi][ni]);
        }
    };

    stage(0, 0);
    stage(1, 32);
    for (int tt = 0; tt < 32; ++tt) {
        if (tt < 31) { WAITVM(4); } else { WAITVM(0); }
        BARRIER();
        CFENCE();
        __builtin_amdgcn_s_setprio(1);
        compute(tt & 1);
        __builtin_amdgcn_s_setprio(0);
        CFENCE();
        BARRIER();
        if (tt < 30) stage(tt & 1, (tt + 2) * 32);
    }

#pragma unroll
    for (int mi = 0; mi < 4; ++mi)
#pragma unroll
        for (int ni = 0; ni < 4; ++ni)
#pragma unroll
            for (int r = 0; r < 4; ++r)
                Th[(size_t)(m0 + wr + mi * 16 + q * 4 + r) * DIM +
                   n0 + wc + ni * 16 + ln15] = (f16)acc[mi][ni][r];
}

// ===========================================================================
// K3: QK^T + softmax -> P, Lsum. r8 form (XCD batch-affinity, 3-buf
// 1-barrier counted-vmcnt, 1 block/CU). 4-buf (r9) regressed — reverted.
// ===========================================================================
__global__ __launch_bounds__(512) void k_attn(const f16* __restrict__ Th,
                                              const f16* __restrict__ Y16,
                                              const float* __restrict__ Z,
                                              f16* __restrict__ P,
                                              float* __restrict__ Lsum) {
    __shared__ __align__(16) f16 sS[3][18432];  // 3 x 36864 B
    __shared__ float redmax[64][8];
    __shared__ float redsum[64][8];
    const int g = blockIdx.x;
    const int b = (g & 7) + 8 * (g >> 6);
    const int l0 = ((g >> 3) & 7) * 64;
    const int t = threadIdx.x;
    const int lane = t & 63, w = t >> 6;
    const int ln15 = lane & 15, q = lane >> 4;
    const bool heavy = (t < 256);
    floatx4 acc[4][4] = {};

    auto stage = [&](int buf, int e0) {
#pragma unroll
        for (int is = 0; is < 4; ++is) {
            int ff = is * 8192 + t * 16;
            const f16* g2;
            if (ff < 4096) {
                g2 = Th + (size_t)(b * LQ + l0 + (ff >> 6)) * DIM + e0 + ((ff & 63) >> 1);
            } else {
                int f2 = ff - 4096;
                g2 = Y16 + (size_t)(b * LK + (f2 >> 6)) * DIM + e0 + ((f2 & 63) >> 1);
            }
            glds16(g2, (char*)&sS[buf][0] + ff);
        }
        if (heavy) {
            int ff = 32768 + t * 16;
            int f2 = ff - 4096;
            const f16* g2 = Y16 + (size_t)(b * LK + (f2 >> 6)) * DIM + e0 + ((f2 & 63) >> 1);
            glds16(g2, (char*)&sS[buf][0] + ff);
        }
    };
    auto compute = [&](int buf) {
        f16x8 th[4];
#pragma unroll
        for (int mi = 0; mi < 4; ++mi)
            th[mi] = *(const f16x8*)&sS[buf][(mi * 16 + ln15) * 32 + q * 8];
#pragma unroll
        for (int ni = 0; ni < 4; ++ni) {
            f16x8 y = *(const f16x8*)&sS[buf][2048 + (w * 64 + ni * 16 + ln15) * 32 + q * 8];
#pragma unroll
            for (int mi = 0; mi < 4; ++mi)
                acc[mi][ni] = MFMA16(th[mi], y, acc[mi][ni]);
        }
    };

    stage(0, 0);
    stage(1, 32);
    int cur = 0;
    for (int tt = 0; tt < 32; ++tt) {
        if (tt < 31) {
            if (heavy) { WAITVM(5); } else { WAITVM(4); }
        } else {
            WAITVM(0);
        }
        BARRIER();
        CFENCE();
        if (tt < 30) stage((cur + 2) % 3, (tt + 2) * 32);
        __builtin_amdgcn_s_setprio(1);
        compute(cur);
        __builtin_amdgcn_s_setprio(0);
        CFENCE();
        cur = (cur == 2) ? 0 : cur + 1;
    }

    float zv[4];
#pragma unroll
    for (int ni = 0; ni < 4; ++ni) zv[ni] = Z[b * LK + w * 64 + ni * 16 + ln15];

    float rmx[4][4];
#pragma unroll
    for (int mi = 0; mi < 4; ++mi)
#pragma unroll
        for (int r = 0; r < 4; ++r) {
            float m = -3.0e38f;
#pragma unroll
            for (int ni = 0; ni < 4; ++ni) m = fmaxf(m, acc[mi][ni][r] + zv[ni]);
#pragma unroll
            for (int off = 1; off < 16; off <<= 1) m = fmaxf(m, __shfl_xor(m, off, 64));
            rmx[mi][r] = m;
        }
    if (ln15 == 0) {
#pragma unroll
        for (int mi = 0; mi < 4; ++mi)
#pragma unroll
            for (int r = 0; r < 4; ++r) redmax[mi * 16 + q * 4 + r][w] = rmx[mi][r];
    }
    __syncthreads();
#pragma unroll
    for (int mi = 0; mi < 4; ++mi)
#pragma unroll
        for (int r = 0; r < 4; ++r) {
            int row = mi * 16 + q * 4 + r;
            float m = redmax[row][0];
#pragma unroll
            for (int j = 1; j < 8; ++j) m = fmaxf(m, redmax[row][j]);
            rmx[mi][r] = m;
        }
    float rsm[4][4] = {};
#pragma unroll
    for (int mi = 0; mi < 4; ++mi)
#pragma unroll
        for (int ni = 0; ni < 4; ++ni)
#pragma unroll
            for (int r = 0; r < 4; ++r) {
                float e = __expf(acc[mi][ni][r] + zv[ni] - rmx[mi][r]);
                acc[mi][ni][r] = e;
                rsm[mi][r] += e;
            }
#pragma unroll
    for (int mi = 0; mi < 4; ++mi)
#pragma unroll
        for (int r = 0; r < 4; ++r) {
            float s = rsm[mi][r];
#pragma unroll
            for (int off = 1; off < 16; off <<= 1) s += __shfl_xor(s, off, 64);
            rsm[mi][r] = s;
        }
    if (ln15 == 0) {
#pragma unroll
        for (int mi = 0; mi < 4; ++mi)
#pragma unroll
            for (int r = 0; r < 4; ++r) redsum[mi * 16 + q * 4 + r][w] = rsm[mi][r];
    }
    __syncthreads();
    if (w == 0 && ln15 == 0) {
#pragma unroll
        for (int mi = 0; mi < 4; ++mi)
#pragma unroll
            for (int r = 0; r < 4; ++r) {
                int row = mi * 16 + q * 4 + r;
                float s = 0.f;
#pragma unroll
                for (int j = 0; j < 8; ++j) s += redsum[row][j];
                Lsum[b * LQ + l0 + row] = s;
            }
    }
#pragma unroll
    for (int mi = 0; mi < 4; ++mi)
#pragma unroll
        for (int ni = 0; ni < 4; ++ni)
#pragma unroll
            for (int r = 0; r < 4; ++r) {
                int row = l0 + mi * 16 + q * 4 + r;
                int col = w * 64 + ni * 16 + ln15;
                P[(size_t)(b * LQ + row) * LK + col] = (f16)acc[mi][ni][r];
            }
}

// ===========================================================================
// K4: O = (P @ y) / Lsum via YT. r8 form (2-buf 32KB, XCD batch-affinity).
// ===========================================================================
__global__ __launch_bounds__(256) void k_pv(const f16* __restrict__ P,
                                            const f16* __restrict__ YT,
                                            const float* __restrict__ Lsum,
                                            float* __restrict__ O) {
    __shared__ __align__(16) f16 sA[2][128 * 32];
    __shared__ __align__(16) f16 sB[2][128 * 32];
    const int t = threadIdx.x;
    const int lane = t & 63, wid = t >> 6;
    const int ln15 = lane & 15, q = lane >> 4;
    const int wr = (wid >> 1) * 64, wc = (wid & 1) * 64;
    const int g = blockIdx.x;
    const int b = (g & 7) + 8 * (g >> 8);
    const int inner = (g >> 3) & 31;
    const int m0 = (inner >> 3) * 128, n0 = (inner & 7) * 128;
    floatx4 acc[4][4] = {};

    const int srow = t >> 2, scol = (t & 3) * 8;
    const f16* gA = P + (size_t)(b * LQ + m0 + srow) * LK + scol;
    const f16* gB = YT + (size_t)(b * DIM + n0 + srow) * LK + scol;

    auto stage = [&](int buf, int k0) {
#pragma unroll
        for (int is = 0; is < 2; ++is) {
            glds16(gA + (size_t)(is * 64) * LK + k0,
                   (char*)&sA[buf][0] + is * 4096 + t * 16);
            glds16(gB + (size_t)(is * 64) * LK + k0,
                   (char*)&sB[buf][0] + is * 4096 + t * 16);
        }
    };
    auto compute = [&](int buf) {
        f16x8 a[4];
#pragma unroll
        for (int mi = 0; mi < 4; ++mi)
            a[mi] = *(const f16x8*)&sA[buf][(wr + mi * 16 + ln15) * 32 + q * 8];
#pragma unroll
        for (int ni = 0; ni < 4; ++ni) {
            f16x8 bv = *(const f16x8*)&sB[buf][(wc + ni * 16 + ln15) * 32 + q * 8];
#pragma unroll
            for (int mi = 0; mi < 4; ++mi) acc[mi][ni] = MFMA16(a[mi], bv, acc[mi][ni]);
        }
    };

    stage(0, 0);
    stage(1, 32);
    for (int tt = 0; tt < 16; ++tt) {
        if (tt < 15) { WAITVM(4); } else { WAITVM(0); }
        BARRIER();
        CFENCE();
        __builtin_amdgcn_s_setprio(1);
        compute(tt & 1);
        __builtin_amdgcn_s_setprio(0);
        CFENCE();
        BARRIER();
        if (tt < 14) stage(tt & 1, (tt + 2) * 32);
    }

    float invl[4][4];
#pragma unroll
    for (int mi = 0; mi < 4; ++mi)
#pragma unroll
        for (int r = 0; r < 4; ++r)
            invl[mi][r] = 1.0f / Lsum[b * LQ + m0 + wr + mi * 16 + q * 4 + r];
#pragma unroll
    for (int mi = 0; mi < 4; ++mi)
#pragma unroll
        for (int ni = 0; ni < 4; ++ni)
#pragma unroll
            for (int r = 0; r < 4; ++r)
                O[(size_t)(b * LQ + m0 + wr + mi * 16 + q * 4 + r) * DIM +
                  n0 + wc + ni * 16 + ln15] = acc[mi][ni][r] * invl[mi][r];
}

// ---------------------------------------------------------------------------
// FUSED (~100.2 MB): X16@0 (P@0 after it dies), Y16@32M, YT@64M, Gh@96M,
//   WT@98M, partial/z/L tail. 5 launches.
// BASIC (86.2 MB): r7 layout, 6 launches.
// ---------------------------------------------------------------------------
extern "C" void kernel_launch(void* const* d_in, const int* in_sizes, int n_in,
                              void* d_out, int out_size, void* d_ws, size_t ws_size,
                              hipStream_t stream) {
    const float* ix = (const float*)d_in[0];
    const float* io = (const float*)d_in[1];
    const float* W = (const float*)d_in[2];
    const float* bb = (const float*)d_in[3];
    float* out = (float*)d_out;
    char* ws = (char*)d_ws;
    f16* Th = (f16*)d_out;

    if (ws_size >= 105054208ull) {  // fused layout
        f16* X16 = (f16*)(ws);
        f16* P = (f16*)(ws);
        f16* Y16 = (f16*)(ws + 33554432);
        f16* YT = (f16*)(ws + 67108864);
        f16* Gh = (f16*)(ws + 100663296);
        f16* WT = (f16*)(ws + 102760448);
        float* partial = (float*)(ws + 104857600);
        float* z = (float*)(ws + 104923136);
        float* L = (float*)(ws + 104988672);

        k_prep_f<<<dim3(2304), dim3(512), 0, stream>>>(ix, io, W, bb, X16, Y16,
                                                       YT, WT, partial);
        k_gram_z<<<dim3(320), dim3(256), 0, stream>>>(WT, partial, Y16, Gh, z, 8);
        k_tgemm<<<dim3(128, 8), dim3(256), 0, stream>>>(X16, Gh, Th);
        k_attn<<<dim3(256), dim3(512), 0, stream>>>(Th, Y16, z, P, L);
        k_pv<<<dim3(1024), dim3(256), 0, stream>>>(P, YT, L, out);
    } else {  // basic layout
        f16* X16 = (f16*)(ws);
        f16* YT = (f16*)(ws);
        f16* Y16 = (f16*)(ws + 33554432);
        f16* P = (f16*)(ws + 67108864);
        f16* WT = (f16*)(ws + 67108864);
        f16* Gh = (f16*)(ws + 83886080);
        float* z = (float*)(ws + 85987328);
        float* L = (float*)(ws + 86052864);
        float* partial = (float*)(ws + 86118400);

        k_prep_b<<<dim3(4608), dim3(256), 0, stream>>>(ix, io, W, bb, X16, Y16,
                                                       WT, partial);
        k_gram_z<<<dim3(320), dim3(256), 0, stream>>>(WT, partial, Y16, Gh, z, 16);
        k_tgemm<<<dim3(128, 8), dim3(256), 0, stream>>>(X16, Gh, Th);
        k_ytrans<<<dim3(32, 8, 16), dim3(256), 0, stream>>>(Y16, YT);
        k_attn<<<dim3(256), dim3(512), 0, stream>>>(Th, Y16, z, P, L);
        k_pv<<<dim3(1024), dim3(256), 0, stream>>>(P, YT, L, out);
    }
}